// Round 7
// baseline (884.048 us; speedup 1.0000x reference)
//
#include <hip/hip_runtime.h>
#include <math.h>

#define N_NODES   50000
#define N_EDGES   800000
#define IN_FEAT   64
#define HIDDEN    32
#define GRID_SZ   4
#define N_GRAPHS  128
#define NEG_SLOPE 0.01f
#define SCAN_BLOCKS 196   // ceil(50000/256)

// ---------------------------------------------------------------------------
__global__ __launch_bounds__(256) void zero_int_kernel(int* __restrict__ p, int n) {
  const int i = blockIdx.x * 256 + threadIdx.x;
  if (i < n) p[i] = 0;
}
__global__ __launch_bounds__(256) void zero_kernel(float* __restrict__ p, int n) {
  const int i = blockIdx.x * 256 + threadIdx.x;
  if (i < n) p[i] = 0.f;
}

// ---------------------------------------------------------------------------
// CSR build: histogram of dst into deg[]
// ---------------------------------------------------------------------------
__global__ __launch_bounds__(256) void hist_kernel(
    const int* __restrict__ dst, int* __restrict__ deg) {
  const int e = blockIdx.x * 256 + threadIdx.x;
  if (e < N_EDGES) atomicAdd(&deg[dst[e]], 1);
}

// multi-block scan, step A: per-block sums of deg -> bsum[SCAN_BLOCKS]
__global__ __launch_bounds__(256) void scanA_kernel(
    const int* __restrict__ deg, int* __restrict__ bsum) {
  const int i = blockIdx.x * 256 + threadIdx.x;
  int v = (i < N_NODES) ? deg[i] : 0;
#pragma unroll
  for (int o = 32; o > 0; o >>= 1) v += __shfl_down(v, o, 64);
  __shared__ int ws[4];
  if ((threadIdx.x & 63) == 0) ws[threadIdx.x >> 6] = v;
  __syncthreads();
  if (threadIdx.x == 0) bsum[blockIdx.x] = ws[0] + ws[1] + ws[2] + ws[3];
}

// step B: single small block scans the 196 block sums -> exclusive offsets
__global__ __launch_bounds__(256) void scanB_kernel(
    int* __restrict__ bsum, int* __restrict__ row_ptr) {
  __shared__ int sh[256];
  const int t = threadIdx.x;
  int v = (t < SCAN_BLOCKS) ? bsum[t] : 0;
  sh[t] = v;
  __syncthreads();
  for (int o = 1; o < 256; o <<= 1) {
    const int u = (t >= o) ? sh[t - o] : 0;
    __syncthreads();
    sh[t] += u;
    __syncthreads();
  }
  bsum[t] = (t == 0) ? 0 : sh[t - 1];   // exclusive
  if (t == 0) row_ptr[N_NODES] = N_EDGES;
}

// step C: per-block exclusive scan + block offset -> row_ptr, cursor
__global__ __launch_bounds__(256) void scanC_kernel(
    const int* __restrict__ deg, const int* __restrict__ bsum,
    int* __restrict__ row_ptr, int* __restrict__ cursor) {
  __shared__ int sh[256];
  const int t = threadIdx.x;
  const int i = blockIdx.x * 256 + t;
  const int v = (i < N_NODES) ? deg[i] : 0;
  sh[t] = v;
  __syncthreads();
  for (int o = 1; o < 256; o <<= 1) {
    const int u = (t >= o) ? sh[t - o] : 0;
    __syncthreads();
    sh[t] += u;
    __syncthreads();
  }
  if (i < N_NODES) {
    const int excl = bsum[blockIdx.x] + sh[t] - v;
    row_ptr[i] = excl;
    cursor[i] = excl;
  }
}

// fill: adj[pos] = src, pos = cursor[dst]++
__global__ __launch_bounds__(256) void fill_kernel(
    const int* __restrict__ src, const int* __restrict__ dst,
    int* __restrict__ cursor, int* __restrict__ adj) {
  const int e = blockIdx.x * 256 + threadIdx.x;
  if (e < N_EDGES) {
    const int pos = atomicAdd(&cursor[dst[e]], 1);
    adj[pos] = src[e];
  }
}

// ---------------------------------------------------------------------------
// gather + fused update: H[n] = leaky(H[n] + sum_{k in row(n)} T[adj[k]])
// ---------------------------------------------------------------------------
__global__ __launch_bounds__(256) void gather_update_kernel(
    const float* __restrict__ T, const int* __restrict__ row_ptr,
    const int* __restrict__ adj, float* __restrict__ H) {
  const int gid = blockIdx.x * 256 + threadIdx.x;
  const int n = gid >> 5;
  const int f = gid & 31;
  if (n >= N_NODES) return;
  const int lo = row_ptr[n], hi = row_ptr[n + 1];
  float acc = 0.f;
  for (int k = lo; k < hi; ++k) {
    const int s = adj[k];
    acc += T[s * HIDDEN + f];
  }
  float v = H[n * HIDDEN + f] + acc;
  v = (v >= 0.f) ? v : NEG_SLOPE * v;
  H[n * HIDDEN + f] = v;
}

// ---------------------------------------------------------------------------
// Input KAN v4: one thread per node, zero LDS.
// Weights read with wave-uniform addresses -> compiler scalarizes to s_load
// (SGPR broadcast); trig computed in-register; 32 accumulators in VGPRs.
// W layout (2,32,64,4): W0[o][i][g] = W[o*256 + i*4 + g], W1 at +8192.
// ---------------------------------------------------------------------------
__global__ __launch_bounds__(256, 4) void kan_input_v4(
    const float* __restrict__ X, const float* __restrict__ W,
    float* __restrict__ H) {
  const int node = blockIdx.x * 256 + threadIdx.x;
  if (node >= N_NODES) return;
  const float* __restrict__ xr = X + node * IN_FEAT;

  float acc[HIDDEN];
#pragma unroll
  for (int o = 0; o < HIDDEN; ++o) acc[o] = 0.f;

#pragma unroll 2
  for (int i4 = 0; i4 < IN_FEAT / 4; ++i4) {
    const float4 xv = reinterpret_cast<const float4*>(xr)[i4];
#pragma unroll
    for (int j = 0; j < 4; ++j) {
      const int i = i4 * 4 + j;
      const float v = (j == 0) ? xv.x : (j == 1) ? xv.y : (j == 2) ? xv.z : xv.w;
      float s1, c1;
      sincosf(v, &s1, &c1);
      const float c2 = c1 * c1 - s1 * s1, s2 = s1 * c1 + c1 * s1;
      const float c3 = c2 * c1 - s2 * s1, s3 = s2 * c1 + c2 * s1;
      const float c4 = c3 * c1 - s3 * s1, s4 = s3 * c1 + c3 * s1;
      const float* __restrict__ wp0 = W + i * GRID_SZ;          // + o*256
      const float* __restrict__ wp1 = W + 8192 + i * GRID_SZ;
#pragma unroll
      for (int o = 0; o < HIDDEN; ++o) {
        const float4 a = *reinterpret_cast<const float4*>(wp0 + o * (IN_FEAT * GRID_SZ));
        const float4 b = *reinterpret_cast<const float4*>(wp1 + o * (IN_FEAT * GRID_SZ));
        acc[o] += c1 * a.x + c2 * a.y + c3 * a.z + c4 * a.w
                + s1 * b.x + s2 * b.y + s3 * b.z + s4 * b.w;
      }
      (void)c2; (void)s2;  // silence unused in odd paths
    }
  }
  float* __restrict__ hr = H + node * HIDDEN;
#pragma unroll
  for (int o4 = 0; o4 < HIDDEN / 4; ++o4)
    reinterpret_cast<float4*>(hr)[o4] =
        make_float4(acc[o4*4], acc[o4*4+1], acc[o4*4+2], acc[o4*4+3]);
}

// ---------------------------------------------------------------------------
// Conv KAN v4: one thread per node, zero LDS, uniform->scalar weight reads.
// W layer (2,32,32,4): W0[o][i][g] = Wl[o*128 + i*4 + g], W1 at +4096.
// ---------------------------------------------------------------------------
__global__ __launch_bounds__(256, 4) void kan_node_v4(
    const float* __restrict__ Hin, const float* __restrict__ W,
    float* __restrict__ T) {
  const int node = blockIdx.x * 256 + threadIdx.x;
  if (node >= N_NODES) return;
  const float* __restrict__ hr = Hin + node * HIDDEN;

  float hv[HIDDEN];
#pragma unroll
  for (int i4 = 0; i4 < HIDDEN / 4; ++i4) {
    const float4 h4 = reinterpret_cast<const float4*>(hr)[i4];
    hv[i4*4+0] = h4.x; hv[i4*4+1] = h4.y; hv[i4*4+2] = h4.z; hv[i4*4+3] = h4.w;
  }

  float acc[HIDDEN];
#pragma unroll
  for (int o = 0; o < HIDDEN; ++o) acc[o] = 0.f;

#pragma unroll 2
  for (int i = 0; i < HIDDEN; ++i) {
    const float v = hv[i];
    float s1, c1;
    sincosf(v, &s1, &c1);
    const float c2 = c1 * c1 - s1 * s1, s2 = s1 * c1 + c1 * s1;
    const float c3 = c2 * c1 - s2 * s1, s3 = s2 * c1 + c2 * s1;
    const float c4 = c3 * c1 - s3 * s1, s4 = s3 * c1 + c3 * s1;
    const float* __restrict__ wp0 = W + i * GRID_SZ;            // + o*128
    const float* __restrict__ wp1 = W + 4096 + i * GRID_SZ;
#pragma unroll
    for (int o = 0; o < HIDDEN; ++o) {
      const float4 a = *reinterpret_cast<const float4*>(wp0 + o * (HIDDEN * GRID_SZ));
      const float4 b = *reinterpret_cast<const float4*>(wp1 + o * (HIDDEN * GRID_SZ));
      acc[o] += c1 * a.x + c2 * a.y + c3 * a.z + c4 * a.w
              + s1 * b.x + s2 * b.y + s3 * b.z + s4 * b.w;
    }
  }
  float* __restrict__ tr = T + node * HIDDEN;
#pragma unroll
  for (int o4 = 0; o4 < HIDDEN / 4; ++o4)
    reinterpret_cast<float4*>(tr)[o4] =
        make_float4(acc[o4*4], acc[o4*4+1], acc[o4*4+2], acc[o4*4+3]);
}

// ---------------------------------------------------------------------------
// pool via run-length over sorted batch: thread = (range r, feat f)
// ---------------------------------------------------------------------------
#define POOL_RANGES 512
__global__ __launch_bounds__(256) void pool_rl(
    const float* __restrict__ H, const int* __restrict__ batch,
    float* __restrict__ sums, float* __restrict__ cnt) {
  const int tid = threadIdx.x;
  const int f = tid & 31;
  const int r = blockIdx.x * 8 + (tid >> 5);
  const int PER = (N_NODES + POOL_RANGES - 1) / POOL_RANGES;  // 98
  int n = r * PER;
  const int end = (n + PER < N_NODES) ? n + PER : N_NODES;
  if (n >= end) return;
  int g = batch[n];
  float acc = 0.f, c = 0.f;
  for (; n < end; ++n) {
    const int gn = batch[n];
    if (gn != g) {
      atomicAdd(&sums[g * HIDDEN + f], acc);
      if (f == 0) atomicAdd(&cnt[g], c);
      g = gn; acc = 0.f; c = 0.f;
    }
    acc += H[n * HIDDEN + f];
    c += 1.f;
  }
  atomicAdd(&sums[g * HIDDEN + f], acc);
  if (f == 0) atomicAdd(&cnt[g], c);
}

// ---------------------------------------------------------------------------
__global__ __launch_bounds__(128) void readout_kernel(
    const float* __restrict__ sums, const float* __restrict__ cnt,
    const float* __restrict__ Wout, const float* __restrict__ bout,
    float* __restrict__ out) {
  const int g = threadIdx.x;
  if (g < N_GRAPHS) {
    const float c = fmaxf(cnt[g], 1.0f);
    float z = 0.f;
#pragma unroll
    for (int i = 0; i < HIDDEN; ++i) {
      const float y = sums[g * HIDDEN + i] / c;
      z += cosf(y) * Wout[i] + sinf(y) * Wout[HIDDEN + i];
    }
    z += bout[0];
    out[g] = 1.0f / (1.0f + expf(-z));
  }
}

// ---------------------------------------------------------------------------
extern "C" void kernel_launch(void* const* d_in, const int* in_sizes, int n_in,
                              void* d_out, int out_size, void* d_ws, size_t ws_size,
                              hipStream_t stream) {
  const float* x        = (const float*)d_in[0];
  const int*   eidx     = (const int*)d_in[1];
  const int*   batch    = (const int*)d_in[2];
  const float* W_in     = (const float*)d_in[3];
  const float* W_conv   = (const float*)d_in[4];
  const float* W_out    = (const float*)d_in[5];
  const float* b_out    = (const float*)d_in[6];
  float* out            = (float*)d_out;

  const int* src = eidx;            // edge_index[0]
  const int* dst = eidx + N_EDGES;  // edge_index[1]

  float* ws = (float*)d_ws;
  float* H       = ws;                         // 1.6M floats
  float* T       = ws + 1600000;               // 1.6M floats
  int*   row_ptr = (int*)(ws + 3200000);       // 50001 (pad 50008)
  int*   deg     = row_ptr + 50008;            // 50000 (pad 50048)
  int*   cursor  = deg + 50048;                // 50000 (pad 50048)
  int*   bsum    = cursor + 50048;             // 256
  int*   adj     = bsum + 256;                 // 800000
  float* SUMS    = (float*)(adj + 800000);     // 4096
  float* CNT     = SUMS + 4096;                // 128

  const int node_blocks = (N_NODES + 255) / 256;     // 196
  const int edge_blocks = (N_EDGES + 255) / 256;     // 3125
  const int gath_blocks = (N_NODES * 32) / 256;      // 6250

  const int WCONV_STRIDE = 2 * HIDDEN * HIDDEN * GRID_SZ;  // 8192

  // --- CSR build (multi-block scan; every kernel chip-wide)
  zero_int_kernel<<<SCAN_BLOCKS, 256, 0, stream>>>(deg, N_NODES);
  hist_kernel<<<edge_blocks, 256, 0, stream>>>(dst, deg);
  scanA_kernel<<<SCAN_BLOCKS, 256, 0, stream>>>(deg, bsum);
  scanB_kernel<<<1, 256, 0, stream>>>(bsum, row_ptr);
  scanC_kernel<<<SCAN_BLOCKS, 256, 0, stream>>>(deg, bsum, row_ptr, cursor);
  fill_kernel<<<edge_blocks, 256, 0, stream>>>(src, dst, cursor, adj);

  // --- input KAN projection: H = KAN_in(x)
  kan_input_v4<<<node_blocks, 256, 0, stream>>>(x, W_in, H);

  // --- layer 0: T = KAN_0(H); H = leaky(H + gather(T))
  kan_node_v4<<<node_blocks, 256, 0, stream>>>(H, W_conv, T);
  gather_update_kernel<<<gath_blocks, 256, 0, stream>>>(T, row_ptr, adj, H);

  // --- layer 1
  kan_node_v4<<<node_blocks, 256, 0, stream>>>(H, W_conv + WCONV_STRIDE, T);
  gather_update_kernel<<<gath_blocks, 256, 0, stream>>>(T, row_ptr, adj, H);

  // --- pool + readout
  zero_kernel<<<17, 256, 0, stream>>>(SUMS, N_GRAPHS * HIDDEN + N_GRAPHS);
  pool_rl<<<POOL_RANGES / 8, 256, 0, stream>>>(H, batch, SUMS, CNT);
  readout_kernel<<<1, 128, 0, stream>>>(SUMS, CNT, W_out, b_out, out);
}

// Round 8
// 382.726 us; speedup vs baseline: 2.3099x; 2.3099x over previous
//
#include <hip/hip_runtime.h>
#include <math.h>

#define N_NODES   50000
#define N_EDGES   800000
#define IN_FEAT   64
#define HIDDEN    32
#define GRID_SZ   4
#define N_GRAPHS  128
#define NEG_SLOPE 0.01f
#define SCAN_BLOCKS 196   // ceil(50000/256)

// ---------------------------------------------------------------------------
__global__ __launch_bounds__(256) void zero_int_kernel(int* __restrict__ p, int n) {
  const int i = blockIdx.x * 256 + threadIdx.x;
  if (i < n) p[i] = 0;
}
__global__ __launch_bounds__(256) void zero_kernel(float* __restrict__ p, int n) {
  const int i = blockIdx.x * 256 + threadIdx.x;
  if (i < n) p[i] = 0.f;
}

// ---------------------------------------------------------------------------
// CSR build: histogram of dst into deg[]
// ---------------------------------------------------------------------------
__global__ __launch_bounds__(256) void hist_kernel(
    const int* __restrict__ dst, int* __restrict__ deg) {
  const int e = blockIdx.x * 256 + threadIdx.x;
  if (e < N_EDGES) atomicAdd(&deg[dst[e]], 1);
}

// multi-block scan, step A: per-block sums of deg -> bsum[SCAN_BLOCKS]
__global__ __launch_bounds__(256) void scanA_kernel(
    const int* __restrict__ deg, int* __restrict__ bsum) {
  const int i = blockIdx.x * 256 + threadIdx.x;
  int v = (i < N_NODES) ? deg[i] : 0;
#pragma unroll
  for (int o = 32; o > 0; o >>= 1) v += __shfl_down(v, o, 64);
  __shared__ int ws[4];
  if ((threadIdx.x & 63) == 0) ws[threadIdx.x >> 6] = v;
  __syncthreads();
  if (threadIdx.x == 0) bsum[blockIdx.x] = ws[0] + ws[1] + ws[2] + ws[3];
}

// step B: single small block scans the 196 block sums -> exclusive offsets
__global__ __launch_bounds__(256) void scanB_kernel(
    int* __restrict__ bsum, int* __restrict__ row_ptr) {
  __shared__ int sh[256];
  const int t = threadIdx.x;
  int v = (t < SCAN_BLOCKS) ? bsum[t] : 0;
  sh[t] = v;
  __syncthreads();
  for (int o = 1; o < 256; o <<= 1) {
    const int u = (t >= o) ? sh[t - o] : 0;
    __syncthreads();
    sh[t] += u;
    __syncthreads();
  }
  bsum[t] = (t == 0) ? 0 : sh[t - 1];   // exclusive
  if (t == 0) row_ptr[N_NODES] = N_EDGES;
}

// step C: per-block exclusive scan + block offset -> row_ptr, cursor
__global__ __launch_bounds__(256) void scanC_kernel(
    const int* __restrict__ deg, const int* __restrict__ bsum,
    int* __restrict__ row_ptr, int* __restrict__ cursor) {
  __shared__ int sh[256];
  const int t = threadIdx.x;
  const int i = blockIdx.x * 256 + t;
  const int v = (i < N_NODES) ? deg[i] : 0;
  sh[t] = v;
  __syncthreads();
  for (int o = 1; o < 256; o <<= 1) {
    const int u = (t >= o) ? sh[t - o] : 0;
    __syncthreads();
    sh[t] += u;
    __syncthreads();
  }
  if (i < N_NODES) {
    const int excl = bsum[blockIdx.x] + sh[t] - v;
    row_ptr[i] = excl;
    cursor[i] = excl;
  }
}

// fill: adj[pos] = src, pos = cursor[dst]++
__global__ __launch_bounds__(256) void fill_kernel(
    const int* __restrict__ src, const int* __restrict__ dst,
    int* __restrict__ cursor, int* __restrict__ adj) {
  const int e = blockIdx.x * 256 + threadIdx.x;
  if (e < N_EDGES) {
    const int pos = atomicAdd(&cursor[dst[e]], 1);
    adj[pos] = src[e];
  }
}

// ---------------------------------------------------------------------------
// gather + fused update: H[n] = leaky(H[n] + sum_{k in row(n)} T[adj[k]])
// ---------------------------------------------------------------------------
__global__ __launch_bounds__(256) void gather_update_kernel(
    const float* __restrict__ T, const int* __restrict__ row_ptr,
    const int* __restrict__ adj, float* __restrict__ H) {
  const int gid = blockIdx.x * 256 + threadIdx.x;
  const int n = gid >> 5;
  const int f = gid & 31;
  if (n >= N_NODES) return;
  const int lo = row_ptr[n], hi = row_ptr[n + 1];
  float acc = 0.f;
  for (int k = lo; k < hi; ++k) {
    const int s = adj[k];
    acc += T[s * HIDDEN + f];
  }
  float v = H[n * HIDDEN + f] + acc;
  v = (v >= 0.f) ? v : NEG_SLOPE * v;
  H[n * HIDDEN + f] = v;
}

// ---------------------------------------------------------------------------
// Input KAN v5: 512 thr, 32 nodes/block, thread=(node-pair,o).
// LDS 80KB -> 2 blocks/CU: weights 64KB (XOR-swizzled float4 slots) +
// trig 16KB chunked over i (4 chunks of 16): tg[node][il][8] so phase-1
// writes are contiguous per 16-lane group (conflict-free, no padding).
// ---------------------------------------------------------------------------
__global__ __launch_bounds__(512, 4) void kan_input_v5(
    const float* __restrict__ X, const float* __restrict__ W,
    float* __restrict__ H) {
  extern __shared__ float smem[];
  float4* __restrict__ w4 = reinterpret_cast<float4*>(smem);   // 4096 float4
  float* __restrict__ tg = smem + 16384;                       // 32*16*8 floats
  const int tid = threadIdx.x;
  const int n0 = blockIdx.x * 32;

  // stage weights, swizzled: slot-in-row = i ^ (o&7)
  const float4* __restrict__ Wg = reinterpret_cast<const float4*>(W);
#pragma unroll
  for (int r = 0; r < 8; ++r) {
    const int q = r * 512 + tid;
    const int slot = (q & ~63) | ((q & 63) ^ ((q >> 6) & 7));
    w4[slot] = Wg[q];
  }

  const int o = tid & 31;
  const int row = tid >> 5;       // 0..15
  const int nA = row * 2, nB = nA + 1;
  const int so = o & 7;
  const int p1_node = tid >> 4;   // 0..31 (phase-1 mapping)
  const int p1_il  = tid & 15;    // 0..15
  const int p1_gn  = n0 + p1_node;
  float accA = 0.f, accB = 0.f;

  for (int c = 0; c < 4; ++c) {
    __syncthreads();  // protect tg from previous chunk's readers
    {  // phase 1: trig for 32 nodes x 16 i  (1 sincos/thread)
      const int i = c * 16 + p1_il;
      const float v = (p1_gn < N_NODES) ? X[p1_gn * IN_FEAT + i] : 0.f;
      float s1, c1;
      sincosf(v, &s1, &c1);
      const float c2 = c1*c1 - s1*s1, s2 = s1*c1 + c1*s1;
      const float c3 = c2*c1 - s2*s1, s3 = s2*c1 + c2*s1;
      const float c4 = c3*c1 - s3*s1, s4 = s3*c1 + c3*s1;
      const int base = p1_node * 128 + p1_il * 8;
      *reinterpret_cast<float4*>(&tg[base])     = make_float4(c1, c2, c3, c4);
      *reinterpret_cast<float4*>(&tg[base + 4]) = make_float4(s1, s2, s3, s4);
    }
    __syncthreads();
    // phase 2: accumulate 16 i for this thread's (nA,nB,o)
#pragma unroll
    for (int il = 0; il < 16; ++il) {
      const int i = c * 16 + il;
      const float4 w0 = w4[o * 64 + (i ^ so)];
      const float4 w1 = w4[2048 + o * 64 + (i ^ so)];
      const float4 cA = *reinterpret_cast<const float4*>(&tg[nA * 128 + il * 8]);
      const float4 sA = *reinterpret_cast<const float4*>(&tg[nA * 128 + il * 8 + 4]);
      const float4 cB = *reinterpret_cast<const float4*>(&tg[nB * 128 + il * 8]);
      const float4 sB = *reinterpret_cast<const float4*>(&tg[nB * 128 + il * 8 + 4]);
      accA += cA.x*w0.x + cA.y*w0.y + cA.z*w0.z + cA.w*w0.w
            + sA.x*w1.x + sA.y*w1.y + sA.z*w1.z + sA.w*w1.w;
      accB += cB.x*w0.x + cB.y*w0.y + cB.z*w0.z + cB.w*w0.w
            + sB.x*w1.x + sB.y*w1.y + sB.z*w1.z + sB.w*w1.w;
    }
  }
  const int gA = n0 + nA, gB = n0 + nB;
  if (gA < N_NODES) H[gA * HIDDEN + o] = accA;
  if (gB < N_NODES) H[gB * HIDDEN + o] = accB;
}

// ---------------------------------------------------------------------------
// Conv KAN v5: 512 thr, 32 nodes/block. LDS 64KB -> 2 blocks/CU:
// weights 32KB swizzled + trig 32KB (no chunking; tg[node][i][8]).
// ---------------------------------------------------------------------------
__global__ __launch_bounds__(512, 4) void kan_node_v5(
    const float* __restrict__ Hin, const float* __restrict__ W,
    float* __restrict__ T) {
  extern __shared__ float smem[];
  float4* __restrict__ w4 = reinterpret_cast<float4*>(smem);   // 2048 float4
  float* __restrict__ tg = smem + 8192;                        // 32*32*8 floats
  const int tid = threadIdx.x;
  const int n0 = blockIdx.x * 32;

  const float4* __restrict__ Wg = reinterpret_cast<const float4*>(W);
#pragma unroll
  for (int r = 0; r < 4; ++r) {
    const int q = r * 512 + tid;
    const int slot = (q & ~31) | ((q & 31) ^ ((q >> 5) & 7));
    w4[slot] = Wg[q];
  }

  // phase 1: trig for 32 nodes x 32 i (2 sincos/thread)
#pragma unroll
  for (int p = 0; p < 2; ++p) {
    const int idx = p * 512 + tid;
    const int node = idx >> 5;    // 0..31
    const int i = idx & 31;
    const int gn = n0 + node;
    const float v = (gn < N_NODES) ? Hin[gn * HIDDEN + i] : 0.f;
    float s1, c1;
    sincosf(v, &s1, &c1);
    const float c2 = c1*c1 - s1*s1, s2 = s1*c1 + c1*s1;
    const float c3 = c2*c1 - s2*s1, s3 = s2*c1 + c2*s1;
    const float c4 = c3*c1 - s3*s1, s4 = s3*c1 + c3*s1;
    const int base = node * 256 + i * 8;
    *reinterpret_cast<float4*>(&tg[base])     = make_float4(c1, c2, c3, c4);
    *reinterpret_cast<float4*>(&tg[base + 4]) = make_float4(s1, s2, s3, s4);
  }
  __syncthreads();

  const int o = tid & 31;
  const int row = tid >> 5;       // 0..15
  const int nA = row * 2, nB = nA + 1;
  const int so = o & 7;
  float accA = 0.f, accB = 0.f;
#pragma unroll 4
  for (int i = 0; i < HIDDEN; ++i) {
    const float4 w0 = w4[o * 32 + (i ^ so)];
    const float4 w1 = w4[1024 + o * 32 + (i ^ so)];
    const float4 cA = *reinterpret_cast<const float4*>(&tg[nA * 256 + i * 8]);
    const float4 sA = *reinterpret_cast<const float4*>(&tg[nA * 256 + i * 8 + 4]);
    const float4 cB = *reinterpret_cast<const float4*>(&tg[nB * 256 + i * 8]);
    const float4 sB = *reinterpret_cast<const float4*>(&tg[nB * 256 + i * 8 + 4]);
    accA += cA.x*w0.x + cA.y*w0.y + cA.z*w0.z + cA.w*w0.w
          + sA.x*w1.x + sA.y*w1.y + sA.z*w1.z + sA.w*w1.w;
    accB += cB.x*w0.x + cB.y*w0.y + cB.z*w0.z + cB.w*w0.w
          + sB.x*w1.x + sB.y*w1.y + sB.z*w1.z + sB.w*w1.w;
  }
  const int gA = n0 + nA, gB = n0 + nB;
  if (gA < N_NODES) T[gA * HIDDEN + o] = accA;
  if (gB < N_NODES) T[gB * HIDDEN + o] = accB;
}

// ---------------------------------------------------------------------------
// pool via run-length over sorted batch: thread = (range r, feat f)
// ---------------------------------------------------------------------------
#define POOL_RANGES 512
__global__ __launch_bounds__(256) void pool_rl(
    const float* __restrict__ H, const int* __restrict__ batch,
    float* __restrict__ sums, float* __restrict__ cnt) {
  const int tid = threadIdx.x;
  const int f = tid & 31;
  const int r = blockIdx.x * 8 + (tid >> 5);
  const int PER = (N_NODES + POOL_RANGES - 1) / POOL_RANGES;  // 98
  int n = r * PER;
  const int end = (n + PER < N_NODES) ? n + PER : N_NODES;
  if (n >= end) return;
  int g = batch[n];
  float acc = 0.f, c = 0.f;
  for (; n < end; ++n) {
    const int gn = batch[n];
    if (gn != g) {
      atomicAdd(&sums[g * HIDDEN + f], acc);
      if (f == 0) atomicAdd(&cnt[g], c);
      g = gn; acc = 0.f; c = 0.f;
    }
    acc += H[n * HIDDEN + f];
    c += 1.f;
  }
  atomicAdd(&sums[g * HIDDEN + f], acc);
  if (f == 0) atomicAdd(&cnt[g], c);
}

// ---------------------------------------------------------------------------
__global__ __launch_bounds__(128) void readout_kernel(
    const float* __restrict__ sums, const float* __restrict__ cnt,
    const float* __restrict__ Wout, const float* __restrict__ bout,
    float* __restrict__ out) {
  const int g = threadIdx.x;
  if (g < N_GRAPHS) {
    const float c = fmaxf(cnt[g], 1.0f);
    float z = 0.f;
#pragma unroll
    for (int i = 0; i < HIDDEN; ++i) {
      const float y = sums[g * HIDDEN + i] / c;
      z += cosf(y) * Wout[i] + sinf(y) * Wout[HIDDEN + i];
    }
    z += bout[0];
    out[g] = 1.0f / (1.0f + expf(-z));
  }
}

// ---------------------------------------------------------------------------
extern "C" void kernel_launch(void* const* d_in, const int* in_sizes, int n_in,
                              void* d_out, int out_size, void* d_ws, size_t ws_size,
                              hipStream_t stream) {
  const float* x        = (const float*)d_in[0];
  const int*   eidx     = (const int*)d_in[1];
  const int*   batch    = (const int*)d_in[2];
  const float* W_in     = (const float*)d_in[3];
  const float* W_conv   = (const float*)d_in[4];
  const float* W_out    = (const float*)d_in[5];
  const float* b_out    = (const float*)d_in[6];
  float* out            = (float*)d_out;

  const int* src = eidx;            // edge_index[0]
  const int* dst = eidx + N_EDGES;  // edge_index[1]

  float* ws = (float*)d_ws;
  float* H       = ws;                         // 1.6M floats
  float* T       = ws + 1600000;               // 1.6M floats
  int*   row_ptr = (int*)(ws + 3200000);       // 50001 (pad 50008)
  int*   deg     = row_ptr + 50008;            // 50000 (pad 50048)
  int*   cursor  = deg + 50048;                // 50000 (pad 50048)
  int*   bsum    = cursor + 50048;             // 256
  int*   adj     = bsum + 256;                 // 800000
  float* SUMS    = (float*)(adj + 800000);     // 4096
  float* CNT     = SUMS + 4096;                // 128

  const int kan_blocks  = (N_NODES + 31) / 32;       // 1563
  const int edge_blocks = (N_EDGES + 255) / 256;     // 3125
  const int gath_blocks = (N_NODES * 32) / 256;      // 6250

  const size_t in_lds   = (16384 + 32 * 16 * 8) * 4;   // 81920 B
  const size_t conv_lds = (8192 + 32 * 32 * 8) * 4;    // 65536 B
  const int WCONV_STRIDE = 2 * HIDDEN * HIDDEN * GRID_SZ;  // 8192

  // --- CSR build (multi-block scan; every kernel chip-wide)
  zero_int_kernel<<<SCAN_BLOCKS, 256, 0, stream>>>(deg, N_NODES);
  hist_kernel<<<edge_blocks, 256, 0, stream>>>(dst, deg);
  scanA_kernel<<<SCAN_BLOCKS, 256, 0, stream>>>(deg, bsum);
  scanB_kernel<<<1, 256, 0, stream>>>(bsum, row_ptr);
  scanC_kernel<<<SCAN_BLOCKS, 256, 0, stream>>>(deg, bsum, row_ptr, cursor);
  fill_kernel<<<edge_blocks, 256, 0, stream>>>(src, dst, cursor, adj);

  // --- input KAN projection: H = KAN_in(x)
  kan_input_v5<<<kan_blocks, 512, in_lds, stream>>>(x, W_in, H);

  // --- layer 0: T = KAN_0(H); H = leaky(H + gather(T))
  kan_node_v5<<<kan_blocks, 512, conv_lds, stream>>>(H, W_conv, T);
  gather_update_kernel<<<gath_blocks, 256, 0, stream>>>(T, row_ptr, adj, H);

  // --- layer 1
  kan_node_v5<<<kan_blocks, 512, conv_lds, stream>>>(H, W_conv + WCONV_STRIDE, T);
  gather_update_kernel<<<gath_blocks, 256, 0, stream>>>(T, row_ptr, adj, H);

  // --- pool + readout
  zero_kernel<<<17, 256, 0, stream>>>(SUMS, N_GRAPHS * HIDDEN + N_GRAPHS);
  pool_rl<<<POOL_RANGES / 8, 256, 0, stream>>>(H, batch, SUMS, CNT);
  readout_kernel<<<1, 128, 0, stream>>>(SUMS, CNT, W_out, b_out, out);
}

// Round 9
// 373.808 us; speedup vs baseline: 2.3650x; 1.0239x over previous
//
#include <hip/hip_runtime.h>
#include <math.h>

#define N_NODES   50000
#define N_EDGES   800000
#define IN_FEAT   64
#define HIDDEN    32
#define GRID_SZ   4
#define N_GRAPHS  128
#define NEG_SLOPE 0.01f
#define SCAN_BLOCKS 196   // ceil(50000/256)

// ---------------------------------------------------------------------------
__global__ __launch_bounds__(256) void zero_int_kernel(int* __restrict__ p, int n) {
  const int i = blockIdx.x * 256 + threadIdx.x;
  if (i < n) p[i] = 0;
}
__global__ __launch_bounds__(256) void zero_kernel(float* __restrict__ p, int n) {
  const int i = blockIdx.x * 256 + threadIdx.x;
  if (i < n) p[i] = 0.f;
}

// ---------------------------------------------------------------------------
// CSR build: histogram of dst into deg[]
// ---------------------------------------------------------------------------
__global__ __launch_bounds__(256) void hist_kernel(
    const int* __restrict__ dst, int* __restrict__ deg) {
  const int e = blockIdx.x * 256 + threadIdx.x;
  if (e < N_EDGES) atomicAdd(&deg[dst[e]], 1);
}

// multi-block scan, step A: per-block sums of deg -> bsum[SCAN_BLOCKS]
__global__ __launch_bounds__(256) void scanA_kernel(
    const int* __restrict__ deg, int* __restrict__ bsum) {
  const int i = blockIdx.x * 256 + threadIdx.x;
  int v = (i < N_NODES) ? deg[i] : 0;
#pragma unroll
  for (int o = 32; o > 0; o >>= 1) v += __shfl_down(v, o, 64);
  __shared__ int ws[4];
  if ((threadIdx.x & 63) == 0) ws[threadIdx.x >> 6] = v;
  __syncthreads();
  if (threadIdx.x == 0) bsum[blockIdx.x] = ws[0] + ws[1] + ws[2] + ws[3];
}

// step B: single small block scans the 196 block sums -> exclusive offsets
__global__ __launch_bounds__(256) void scanB_kernel(
    int* __restrict__ bsum, int* __restrict__ row_ptr) {
  __shared__ int sh[256];
  const int t = threadIdx.x;
  int v = (t < SCAN_BLOCKS) ? bsum[t] : 0;
  sh[t] = v;
  __syncthreads();
  for (int o = 1; o < 256; o <<= 1) {
    const int u = (t >= o) ? sh[t - o] : 0;
    __syncthreads();
    sh[t] += u;
    __syncthreads();
  }
  bsum[t] = (t == 0) ? 0 : sh[t - 1];   // exclusive
  if (t == 0) row_ptr[N_NODES] = N_EDGES;
}

// step C: per-block exclusive scan + block offset -> row_ptr, cursor
__global__ __launch_bounds__(256) void scanC_kernel(
    const int* __restrict__ deg, const int* __restrict__ bsum,
    int* __restrict__ row_ptr, int* __restrict__ cursor) {
  __shared__ int sh[256];
  const int t = threadIdx.x;
  const int i = blockIdx.x * 256 + t;
  const int v = (i < N_NODES) ? deg[i] : 0;
  sh[t] = v;
  __syncthreads();
  for (int o = 1; o < 256; o <<= 1) {
    const int u = (t >= o) ? sh[t - o] : 0;
    __syncthreads();
    sh[t] += u;
    __syncthreads();
  }
  if (i < N_NODES) {
    const int excl = bsum[blockIdx.x] + sh[t] - v;
    row_ptr[i] = excl;
    cursor[i] = excl;
  }
}

// fill: adj[pos] = src, pos = cursor[dst]++
__global__ __launch_bounds__(256) void fill_kernel(
    const int* __restrict__ src, const int* __restrict__ dst,
    int* __restrict__ cursor, int* __restrict__ adj) {
  const int e = blockIdx.x * 256 + threadIdx.x;
  if (e < N_EDGES) {
    const int pos = atomicAdd(&cursor[dst[e]], 1);
    adj[pos] = src[e];
  }
}

// ---------------------------------------------------------------------------
// gather + fused update: H[n] = leaky(H[n] + sum_{k in row(n)} T[adj[k]])
// ---------------------------------------------------------------------------
__global__ __launch_bounds__(256) void gather_update_kernel(
    const float* __restrict__ T, const int* __restrict__ row_ptr,
    const int* __restrict__ adj, float* __restrict__ H) {
  const int gid = blockIdx.x * 256 + threadIdx.x;
  const int n = gid >> 5;
  const int f = gid & 31;
  if (n >= N_NODES) return;
  const int lo = row_ptr[n], hi = row_ptr[n + 1];
  float acc = 0.f;
  for (int k = lo; k < hi; ++k) {
    const int s = adj[k];
    acc += T[s * HIDDEN + f];
  }
  float v = H[n * HIDDEN + f] + acc;
  v = (v >= 0.f) ? v : NEG_SLOPE * v;
  H[n * HIDDEN + f] = v;
}

// ---------------------------------------------------------------------------
// Input KAN v6: 256 thr, 64 nodes/block, thread = (node-pair, o-quad), 8 acc.
// LDS: weights 64KB XOR-swizzled (slot = i ^ (o>>2)); trig (c1,s1) only,
// rows padded to 132 floats -> conflict-free b128 reads. i chunked 4x16.
// Per i-step: 9 b128 LDS reads for 64 FMA (2.25 B/FMA, 3x less than v5).
// ---------------------------------------------------------------------------
__global__ __launch_bounds__(256, 2) void kan_input_v6(
    const float* __restrict__ X, const float* __restrict__ W,
    float* __restrict__ H) {
  extern __shared__ float smem[];
  float4* __restrict__ w4 = reinterpret_cast<float4*>(smem);  // 4096 float4
  float* __restrict__ tg = smem + 16384;                      // 16*132 floats
  const int tid = threadIdx.x;
  const int n0 = blockIdx.x * 64;

  // stage weights swizzled: slot-in-row = i ^ ((o>>2)&7)
  const float4* __restrict__ Wg = reinterpret_cast<const float4*>(W);
#pragma unroll
  for (int r = 0; r < 16; ++r) {
    const int q = r * 256 + tid;
    const int i = q & 63;
    const int o = (q >> 6) & 31;
    const int slot = (q & ~63) | (i ^ ((o >> 2) & 7));
    w4[slot] = Wg[q];
  }

  const int og = tid & 7;        // o-quad: outputs 4*og .. 4*og+3
  const int pairIdx = tid >> 3;  // 0..31 -> nodes 2*pairIdx, +1
  const int nA = n0 + 2 * pairIdx;
  const int nB = nA + 1;

  float accA[4] = {0.f, 0.f, 0.f, 0.f};
  float accB[4] = {0.f, 0.f, 0.f, 0.f};

  for (int c = 0; c < 4; ++c) {
    __syncthreads();   // protect tg from previous chunk's readers (+staging)
    // phase 1: (c1,s1) for 64 nodes x 16 i
#pragma unroll
    for (int p = 0; p < 4; ++p) {
      const int i_l = tid & 15;
      const int node = p * 16 + (tid >> 4);
      const int gn = n0 + node;
      const float v = (gn < N_NODES) ? X[gn * IN_FEAT + c * 16 + i_l] : 0.f;
      float s1, c1;
      sincosf(v, &s1, &c1);
      *reinterpret_cast<float2*>(&tg[i_l * 132 + node * 2]) = make_float2(c1, s1);
    }
    __syncthreads();
    // phase 2: accumulate 16 i
#pragma unroll
    for (int il = 0; il < 16; ++il) {
      const float4 t4 = *reinterpret_cast<const float4*>(&tg[il * 132 + pairIdx * 4]);
      const float c1 = t4.x, s1 = t4.y;   // node A
      const float d1 = t4.z, r1 = t4.w;   // node B
      const float c2 = c1*c1 - s1*s1, s2 = s1*c1 + c1*s1;
      const float c3 = c2*c1 - s2*s1, s3 = s2*c1 + c2*s1;
      const float c4 = c3*c1 - s3*s1, s4 = s3*c1 + c3*s1;
      const float d2 = d1*d1 - r1*r1, r2 = r1*d1 + d1*r1;
      const float d3 = d2*d1 - r2*r1, r3 = r2*d1 + d2*r1;
      const float d4 = d3*d1 - r3*r1, r4 = r3*d1 + d3*r1;
      const int slot = (c * 16 + il) ^ og;
#pragma unroll
      for (int oq = 0; oq < 4; ++oq) {
        const float4 a = w4[(4 * og + oq) * 64 + slot];
        const float4 b = w4[2048 + (4 * og + oq) * 64 + slot];
        accA[oq] += c1*a.x + c2*a.y + c3*a.z + c4*a.w
                  + s1*b.x + s2*b.y + s3*b.z + s4*b.w;
        accB[oq] += d1*a.x + d2*a.y + d3*a.z + d4*a.w
                  + r1*b.x + r2*b.y + r3*b.z + r4*b.w;
      }
    }
  }
  if (nA < N_NODES)
    *reinterpret_cast<float4*>(&H[nA * HIDDEN + 4 * og]) =
        make_float4(accA[0], accA[1], accA[2], accA[3]);
  if (nB < N_NODES)
    *reinterpret_cast<float4*>(&H[nB * HIDDEN + 4 * og]) =
        make_float4(accB[0], accB[1], accB[2], accB[3]);
}

// ---------------------------------------------------------------------------
// Conv KAN v6: same structure, 32 i in one pass. LDS 48.5KB -> 3 blocks/CU.
// ---------------------------------------------------------------------------
__global__ __launch_bounds__(256, 3) void kan_node_v6(
    const float* __restrict__ Hin, const float* __restrict__ W,
    float* __restrict__ T) {
  extern __shared__ float smem[];
  float4* __restrict__ w4 = reinterpret_cast<float4*>(smem);  // 2048 float4
  float* __restrict__ tg = smem + 8192;                       // 32*132 floats
  const int tid = threadIdx.x;
  const int n0 = blockIdx.x * 64;

  const float4* __restrict__ Wg = reinterpret_cast<const float4*>(W);
#pragma unroll
  for (int r = 0; r < 8; ++r) {
    const int q = r * 256 + tid;
    const int i = q & 31;
    const int o = (q >> 5) & 31;
    const int slot = (q & ~31) | (i ^ ((o >> 2) & 7));
    w4[slot] = Wg[q];
  }

  // phase 1: (c1,s1) for 64 nodes x 32 i
#pragma unroll
  for (int p = 0; p < 8; ++p) {
    const int i_l = tid & 31;
    const int node = p * 8 + (tid >> 5);
    const int gn = n0 + node;
    const float v = (gn < N_NODES) ? Hin[gn * HIDDEN + i_l] : 0.f;
    float s1, c1;
    sincosf(v, &s1, &c1);
    *reinterpret_cast<float2*>(&tg[i_l * 132 + node * 2]) = make_float2(c1, s1);
  }
  __syncthreads();

  const int og = tid & 7;
  const int pairIdx = tid >> 3;
  const int nA = n0 + 2 * pairIdx;
  const int nB = nA + 1;

  float accA[4] = {0.f, 0.f, 0.f, 0.f};
  float accB[4] = {0.f, 0.f, 0.f, 0.f};

#pragma unroll 8
  for (int il = 0; il < 32; ++il) {
    const float4 t4 = *reinterpret_cast<const float4*>(&tg[il * 132 + pairIdx * 4]);
    const float c1 = t4.x, s1 = t4.y;
    const float d1 = t4.z, r1 = t4.w;
    const float c2 = c1*c1 - s1*s1, s2 = s1*c1 + c1*s1;
    const float c3 = c2*c1 - s2*s1, s3 = s2*c1 + c2*s1;
    const float c4 = c3*c1 - s3*s1, s4 = s3*c1 + c3*s1;
    const float d2 = d1*d1 - r1*r1, r2 = r1*d1 + d1*r1;
    const float d3 = d2*d1 - r2*r1, r3 = r2*d1 + d2*r1;
    const float d4 = d3*d1 - r3*r1, r4 = r3*d1 + d3*r1;
    const int slot = il ^ og;
#pragma unroll
    for (int oq = 0; oq < 4; ++oq) {
      const float4 a = w4[(4 * og + oq) * 32 + slot];
      const float4 b = w4[1024 + (4 * og + oq) * 32 + slot];
      accA[oq] += c1*a.x + c2*a.y + c3*a.z + c4*a.w
                + s1*b.x + s2*b.y + s3*b.z + s4*b.w;
      accB[oq] += d1*a.x + d2*a.y + d3*a.z + d4*a.w
                + r1*b.x + r2*b.y + r3*b.z + r4*b.w;
    }
  }
  if (nA < N_NODES)
    *reinterpret_cast<float4*>(&T[nA * HIDDEN + 4 * og]) =
        make_float4(accA[0], accA[1], accA[2], accA[3]);
  if (nB < N_NODES)
    *reinterpret_cast<float4*>(&T[nB * HIDDEN + 4 * og]) =
        make_float4(accB[0], accB[1], accB[2], accB[3]);
}

// ---------------------------------------------------------------------------
// pool via run-length over sorted batch: thread = (range r, feat f)
// ---------------------------------------------------------------------------
#define POOL_RANGES 512
__global__ __launch_bounds__(256) void pool_rl(
    const float* __restrict__ H, const int* __restrict__ batch,
    float* __restrict__ sums, float* __restrict__ cnt) {
  const int tid = threadIdx.x;
  const int f = tid & 31;
  const int r = blockIdx.x * 8 + (tid >> 5);
  const int PER = (N_NODES + POOL_RANGES - 1) / POOL_RANGES;  // 98
  int n = r * PER;
  const int end = (n + PER < N_NODES) ? n + PER : N_NODES;
  if (n >= end) return;
  int g = batch[n];
  float acc = 0.f, c = 0.f;
  for (; n < end; ++n) {
    const int gn = batch[n];
    if (gn != g) {
      atomicAdd(&sums[g * HIDDEN + f], acc);
      if (f == 0) atomicAdd(&cnt[g], c);
      g = gn; acc = 0.f; c = 0.f;
    }
    acc += H[n * HIDDEN + f];
    c += 1.f;
  }
  atomicAdd(&sums[g * HIDDEN + f], acc);
  if (f == 0) atomicAdd(&cnt[g], c);
}

// ---------------------------------------------------------------------------
__global__ __launch_bounds__(128) void readout_kernel(
    const float* __restrict__ sums, const float* __restrict__ cnt,
    const float* __restrict__ Wout, const float* __restrict__ bout,
    float* __restrict__ out) {
  const int g = threadIdx.x;
  if (g < N_GRAPHS) {
    const float c = fmaxf(cnt[g], 1.0f);
    float z = 0.f;
#pragma unroll
    for (int i = 0; i < HIDDEN; ++i) {
      const float y = sums[g * HIDDEN + i] / c;
      z += cosf(y) * Wout[i] + sinf(y) * Wout[HIDDEN + i];
    }
    z += bout[0];
    out[g] = 1.0f / (1.0f + expf(-z));
  }
}

// ---------------------------------------------------------------------------
extern "C" void kernel_launch(void* const* d_in, const int* in_sizes, int n_in,
                              void* d_out, int out_size, void* d_ws, size_t ws_size,
                              hipStream_t stream) {
  const float* x        = (const float*)d_in[0];
  const int*   eidx     = (const int*)d_in[1];
  const int*   batch    = (const int*)d_in[2];
  const float* W_in     = (const float*)d_in[3];
  const float* W_conv   = (const float*)d_in[4];
  const float* W_out    = (const float*)d_in[5];
  const float* b_out    = (const float*)d_in[6];
  float* out            = (float*)d_out;

  const int* src = eidx;            // edge_index[0]
  const int* dst = eidx + N_EDGES;  // edge_index[1]

  float* ws = (float*)d_ws;
  float* H       = ws;                         // 1.6M floats
  float* T       = ws + 1600000;               // 1.6M floats
  int*   row_ptr = (int*)(ws + 3200000);       // 50001 (pad 50008)
  int*   deg     = row_ptr + 50008;            // 50000 (pad 50048)
  int*   cursor  = deg + 50048;                // 50000 (pad 50048)
  int*   bsum    = cursor + 50048;             // 256
  int*   adj     = bsum + 256;                 // 800000
  float* SUMS    = (float*)(adj + 800000);     // 4096
  float* CNT     = SUMS + 4096;                // 128

  const int kan_blocks  = (N_NODES + 63) / 64;       // 782
  const int edge_blocks = (N_EDGES + 255) / 256;     // 3125
  const int gath_blocks = (N_NODES * 32) / 256;      // 6250

  const size_t in_lds   = (16384 + 16 * 132) * 4;    // 73984 B  (2 blocks/CU)
  const size_t conv_lds = (8192 + 32 * 132) * 4;     // 49664 B  (3 blocks/CU)
  const int WCONV_STRIDE = 2 * HIDDEN * HIDDEN * GRID_SZ;  // 8192

  // --- CSR build (multi-block scan; every kernel chip-wide)
  zero_int_kernel<<<SCAN_BLOCKS, 256, 0, stream>>>(deg, N_NODES);
  hist_kernel<<<edge_blocks, 256, 0, stream>>>(dst, deg);
  scanA_kernel<<<SCAN_BLOCKS, 256, 0, stream>>>(deg, bsum);
  scanB_kernel<<<1, 256, 0, stream>>>(bsum, row_ptr);
  scanC_kernel<<<SCAN_BLOCKS, 256, 0, stream>>>(deg, bsum, row_ptr, cursor);
  fill_kernel<<<edge_blocks, 256, 0, stream>>>(src, dst, cursor, adj);

  // --- input KAN projection: H = KAN_in(x)
  kan_input_v6<<<kan_blocks, 256, in_lds, stream>>>(x, W_in, H);

  // --- layer 0: T = KAN_0(H); H = leaky(H + gather(T))
  kan_node_v6<<<kan_blocks, 256, conv_lds, stream>>>(H, W_conv, T);
  gather_update_kernel<<<gath_blocks, 256, 0, stream>>>(T, row_ptr, adj, H);

  // --- layer 1
  kan_node_v6<<<kan_blocks, 256, conv_lds, stream>>>(H, W_conv + WCONV_STRIDE, T);
  gather_update_kernel<<<gath_blocks, 256, 0, stream>>>(T, row_ptr, adj, H);

  // --- pool + readout
  zero_kernel<<<17, 256, 0, stream>>>(SUMS, N_GRAPHS * HIDDEN + N_GRAPHS);
  pool_rl<<<POOL_RANGES / 8, 256, 0, stream>>>(H, batch, SUMS, CNT);
  readout_kernel<<<1, 128, 0, stream>>>(SUMS, CNT, W_out, b_out, out);
}